// Round 18
// baseline (532.904 us; speedup 1.0000x reference)
//
#include <hip/hip_runtime.h>
#include <hip/hip_bf16.h>

typedef __bf16 bf16_t;
typedef __bf16 bf16x4 __attribute__((ext_vector_type(4)));
typedef __bf16 bf16x8 __attribute__((ext_vector_type(8)));
typedef float f32x4 __attribute__((ext_vector_type(4)));

#define GLOAD_LDS16(g, l)                                                      \
  __builtin_amdgcn_global_load_lds(                                            \
      (const __attribute__((address_space(1))) void*)(g),                      \
      (__attribute__((address_space(3))) void*)(l), 16, 0, 0)

#define MFMA(a, b, c) __builtin_amdgcn_mfma_f32_16x16x32_bf16((a), (b), (c), 0, 0, 0)

// ---------------------------------------------------------------------------
// ROUND 18: faithful m201-style 8-phase schedule (T2+T3+T4+T5) for the four
// K=1024 step GEMMs. 256x256 tile, BK=64, 512 thr, 8 waves 2Mx4N, per-wave
// 128x64 (acc[8][4]=128 regs). LDS 128KB = 2 K-tile slots x (A[256][64] 32KB
// + B[256][64] 32KB); halves = 128 rows (16KB, 2 loads/thread).
//
// Phases per iter (2 K-tiles: 2t->slot0, 2t+1->slot1); quadrant q(mq,nq):
//   ph0 s0.q00 (12 rd)  ph1 s0.q01 (4)  ph2 s0.q11 (8)  ph3 s0.q10 (0)
//   ph4 s1.q00 (12)     ph5 s1.q01 (4)  ph6 s1.q11 (8)  ph7 s1.q10 (0)
// Region last-read (union over waves): s0.B ph1, s0.A ph2, s1.B ph5, s1.A ph6.
// Stage ring (1 half/phase; stage >= 1 full phase after last read, >= 4
// phases before first read of new content):
//   ph0: s1.A0<-tile 2t+1   ph1: s1.A1<-2t+1   (old s1.A last read prev ph6)
//   ph2: s0.B0<-2t+2        ph3: s0.B1<-2t+2   (s0.B last read ph1)
//   ph4: s0.A0<-2t+2        ph5: s0.A1<-2t+2   (s0.A last read ph2)
//   ph6: s1.B0<-2t+3        ph7: s1.B1<-2t+3   (s1.B last read ph5)
// vmcnt ledger (2 loads/stage, in-order retirement): entering ph0 the queue
// is [s1B0,s1B1]; ph0-3 push 4 ops -> 12 loads; vmcnt(4) @ph3-end retires
// [s1B0,s1B1,s1A0,s1A1] == slot1 complete for ph4. ph4-7 push 4 ops;
// vmcnt(4) @ph7-end retires [s0B0,s0B1,s0A0,s0A1] == slot0 complete for
// next ph0. Never drains to 0 (T4). Prologue issues s0{B0,B1,A0,A1},
// s1{B0,B1}; vmcnt(4) -> queue == steady state.
// Phase body: {ds_reads; stage; s_barrier; lgkmcnt(0); sched_barrier(0)
// (rule #18 fence); setprio(1); 16 MFMA; setprio(0); [vmcnt(4)]; s_barrier}.
// Swizzle: r15's verified unit^(row&7) pre-swizzled-global / linear-dest.
// ---------------------------------------------------------------------------
__global__ __launch_bounds__(512, 2) void gemm8_kernel(
    const bf16_t* __restrict__ A, const bf16_t* __restrict__ Bt,
    int Nc, int mode,
    const bf16_t* __restrict__ WxIn, bf16_t* __restrict__ UnextOrWx,
    float* __restrict__ Out, const float* __restrict__ thresh_p)
{
  __shared__ __align__(16) char smem[131072];
  bf16_t* lds = (bf16_t*)smem;     // slot stride 32768 elems; B at +16384

  const int tid = threadIdx.x;
  const int wid = tid >> 6, lane = tid & 63;
  const int wr = wid >> 2, wc = wid & 3;         // 2M x 4N wave grid
  const int lr = lane & 15, kg = lane >> 4;

  const int per = gridDim.x >> 3;                // 512 % 8 == 0
  const int logical = (blockIdx.x & 7) * per + (blockIdx.x >> 3);
  const int ntn = Nc >> 8;                       // 4
  const int tileN = (logical % ntn) << 8;
  const int tileM = (logical / ntn) << 8;

  // Half-tile staging: 128 rows x 64 bf16 = 1024 16B-units; 2 loads/thread.
  const int f1 = tid + 512;
  const int rowS[2] = { tid >> 3, f1 >> 3 };
  const int ugS[2]  = { (tid & 7) ^ (rowS[0] & 7), (f1 & 7) ^ (rowS[1] & 7) };
  const int dstS[2] = { tid * 8, f1 * 8 };

  auto stageA = [&](int h, int kt, int slot) {
    #pragma unroll
    for (int j = 0; j < 2; ++j)
      GLOAD_LDS16(A + (size_t)(tileM + h * 128 + rowS[j]) * 1024 + (kt << 6) + ugS[j] * 8,
                  lds + slot * 32768 + h * 8192 + dstS[j]);
  };
  auto stageB = [&](int h, int kt, int slot) {
    #pragma unroll
    for (int j = 0; j < 2; ++j)
      GLOAD_LDS16(Bt + (size_t)(tileN + h * 128 + rowS[j]) * 1024 + (kt << 6) + ugS[j] * 8,
                  lds + slot * 32768 + 16384 + h * 8192 + dstS[j]);
  };
  auto readA = [&](int mi, int ks, int slot) -> bf16x8 {
    const int R = wr * 128 + mi * 16 + lr;
    const int ul = (ks * 4 + kg) ^ (R & 7);
    return *(const bf16x8*)(lds + slot * 32768 + R * 64 + ul * 8);
  };
  auto readB = [&](int ni, int ks, int slot) -> bf16x8 {
    const int C = wc * 64 + ni * 16 + lr;
    const int ul = (ks * 4 + kg) ^ (C & 7);
    return *(const bf16x8*)(lds + slot * 32768 + 16384 + C * 64 + ul * 8);
  };

  f32x4 acc[8][4] = {};
  bf16x8 aL[4][2], aH[4][2], bL[2][2], bH[2][2];

  auto loadALo = [&](int s) {
    #pragma unroll
    for (int mi = 0; mi < 4; ++mi) { aL[mi][0] = readA(mi, 0, s); aL[mi][1] = readA(mi, 1, s); }
  };
  auto loadAHi = [&](int s) {
    #pragma unroll
    for (int mi = 0; mi < 4; ++mi) { aH[mi][0] = readA(mi + 4, 0, s); aH[mi][1] = readA(mi + 4, 1, s); }
  };
  auto loadBLo = [&](int s) {
    #pragma unroll
    for (int ni = 0; ni < 2; ++ni) { bL[ni][0] = readB(ni, 0, s); bL[ni][1] = readB(ni, 1, s); }
  };
  auto loadBHi = [&](int s) {
    #pragma unroll
    for (int ni = 0; ni < 2; ++ni) { bH[ni][0] = readB(ni + 2, 0, s); bH[ni][1] = readB(ni + 2, 1, s); }
  };
  auto q00 = [&]() {
    #pragma unroll
    for (int mi = 0; mi < 4; ++mi)
      #pragma unroll
      for (int ni = 0; ni < 2; ++ni) {
        acc[mi][ni] = MFMA(aL[mi][0], bL[ni][0], acc[mi][ni]);
        acc[mi][ni] = MFMA(aL[mi][1], bL[ni][1], acc[mi][ni]);
      }
  };
  auto q01 = [&]() {
    #pragma unroll
    for (int mi = 0; mi < 4; ++mi)
      #pragma unroll
      for (int ni = 0; ni < 2; ++ni) {
        acc[mi][ni + 2] = MFMA(aL[mi][0], bH[ni][0], acc[mi][ni + 2]);
        acc[mi][ni + 2] = MFMA(aL[mi][1], bH[ni][1], acc[mi][ni + 2]);
      }
  };
  auto q11 = [&]() {
    #pragma unroll
    for (int mi = 0; mi < 4; ++mi)
      #pragma unroll
      for (int ni = 0; ni < 2; ++ni) {
        acc[mi + 4][ni + 2] = MFMA(aH[mi][0], bH[ni][0], acc[mi + 4][ni + 2]);
        acc[mi + 4][ni + 2] = MFMA(aH[mi][1], bH[ni][1], acc[mi + 4][ni + 2]);
      }
  };
  auto q10 = [&]() {
    #pragma unroll
    for (int mi = 0; mi < 4; ++mi)
      #pragma unroll
      for (int ni = 0; ni < 2; ++ni) {
        acc[mi + 4][ni] = MFMA(aH[mi][0], bL[ni][0], acc[mi + 4][ni]);
        acc[mi + 4][ni] = MFMA(aH[mi][1], bL[ni][1], acc[mi + 4][ni]);
      }
  };

#define PH_SYNC()                                                              \
  do {                                                                         \
    __builtin_amdgcn_s_barrier();                                              \
    asm volatile("s_waitcnt lgkmcnt(0)" ::: "memory");                         \
    __builtin_amdgcn_sched_barrier(0);                                         \
    __builtin_amdgcn_s_setprio(1);                                             \
  } while (0)
#define PH_END()                                                               \
  do {                                                                         \
    __builtin_amdgcn_s_setprio(0);                                             \
    __builtin_amdgcn_s_barrier();                                              \
  } while (0)
#define PH_END_VM()                                                            \
  do {                                                                         \
    __builtin_amdgcn_s_setprio(0);                                             \
    asm volatile("s_waitcnt vmcnt(4)" ::: "memory");                           \
    __builtin_amdgcn_s_barrier();                                              \
  } while (0)

  // Prologue: tile0 -> slot0 (all 4 halves), tile1's B -> slot1.
  stageB(0, 0, 0); stageB(1, 0, 0); stageA(0, 0, 0); stageA(1, 0, 0);
  stageB(0, 1, 1); stageB(1, 1, 1);
  asm volatile("s_waitcnt vmcnt(4)" ::: "memory");   // tile0 landed
  __builtin_amdgcn_s_barrier();

  for (int it = 0; it < 8; ++it) {                   // 2 K-tiles / iter
    const int t1 = 2 * it + 1;
    const int n0 = (2 * it + 2) & 15;                // wrap refetch benign
    const int n1 = (2 * it + 3) & 15;

    loadALo(0); loadBLo(0); stageA(0, t1, 1);        // ph0: s0.q00
    PH_SYNC(); q00(); PH_END();
    loadBHi(0);             stageA(1, t1, 1);        // ph1: s0.q01
    PH_SYNC(); q01(); PH_END();
    loadAHi(0);             stageB(0, n0, 0);        // ph2: s0.q11
    PH_SYNC(); q11(); PH_END();
                            stageB(1, n0, 0);        // ph3: s0.q10
    PH_SYNC(); q10(); PH_END_VM();                   // slot1 complete

    loadALo(1); loadBLo(1); stageA(0, n0, 0);        // ph4: s1.q00
    PH_SYNC(); q00(); PH_END();
    loadBHi(1);             stageA(1, n0, 0);        // ph5: s1.q01
    PH_SYNC(); q01(); PH_END();
    loadAHi(1);             stageB(0, n1, 1);        // ph6: s1.q11
    PH_SYNC(); q11(); PH_END();
                            stageB(1, n1, 1);        // ph7: s1.q10
    PH_SYNC(); q10(); PH_END_VM();                   // slot0 complete
  }

  const float th = *thresh_p;

  if (mode <= 1) {
    // Repack epilogue: canonical row-major bf16, 8B/lane full-line stores.
    asm volatile("s_waitcnt vmcnt(0)" ::: "memory"); // stray stages landed
    __syncthreads();
    float* Tl = (float*)smem;                        // [32][260] f32
    #pragma unroll
    for (int c = 0; c < 8; ++c) {                    // 32-row chunks of 256
      if (c) __syncthreads();
      if (wr == (c >> 2)) {
        #pragma unroll
        for (int mj = 0; mj < 2; ++mj) {
          const int mi = (c & 3) * 2 + mj;
          const int rl = mj * 16 + kg * 4;
          #pragma unroll
          for (int ni = 0; ni < 4; ++ni) {
            const int cl = wc * 64 + ni * 16 + lr;
            #pragma unroll
            for (int r = 0; r < 4; ++r)
              Tl[(rl + r) * 260 + cl] = acc[mi][ni][r];
          }
        }
      }
      __syncthreads();
      #pragma unroll
      for (int j = 0; j < 4; ++j) {
        const int f  = j * 512 + tid;                // 0..2047
        const int rl = f >> 6;                       // 0..31
        const int c4 = (f & 63) * 4;                 // 0..252
        const f32x4 v = *(const f32x4*)&Tl[rl * 260 + c4];
        const int grow = tileM + c * 32 + rl;
        const size_t gidx = (size_t)grow * Nc + tileN + c4;
        bf16x4 ov;
        if (mode == 1) {
          const bf16x4 wx = *(const bf16x4*)&WxIn[gidx];
          #pragma unroll
          for (int e = 0; e < 4; ++e) {
            const float a  = fabsf(v[e]) - th;
            const float zn = (a > 0.f) ? copysignf(a, v[e]) : 0.f;
            ov[e] = (bf16_t)(zn + (float)wx[e]);
          }
        } else {
          #pragma unroll
          for (int e = 0; e < 4; ++e) ov[e] = (bf16_t)v[e];
        }
        *(bf16x4*)&UnextOrWx[gidx] = ov;
      }
    }
  } else {
    // mode 2: z = st(acc), fused transpose -> Out[b][k][p].
    #pragma unroll
    for (int mi = 0; mi < 8; ++mi)
      #pragma unroll
      for (int ni = 0; ni < 4; ++ni)
        #pragma unroll
        for (int r = 0; r < 4; ++r) {
          const float v = acc[mi][ni][r];
          const float a = fabsf(v) - th;
          acc[mi][ni][r] = (a > 0.f) ? copysignf(a, v) : 0.f;
        }
    asm volatile("s_waitcnt vmcnt(0)" ::: "memory");
    __syncthreads();
    float* Tl = (float*)smem;                        // [32][260] f32
    const int    bb    = tileM >> 10;
    const size_t obase = (size_t)bb * 1048576 + (size_t)(tileM & 1023);
    #pragma unroll
    for (int ch = 0; ch < 8; ++ch) {                 // 32-k-col chunks of 256
      if (ch) __syncthreads();
      if (wc == (ch >> 1)) {
        #pragma unroll
        for (int nj = 0; nj < 2; ++nj) {
          const int ni = (ch & 1) * 2 + nj;
          const int cp = nj * 16 + lr;               // 0..31
          #pragma unroll
          for (int mi = 0; mi < 8; ++mi)
            #pragma unroll
            for (int r = 0; r < 4; ++r)
              Tl[cp * 260 + wr * 128 + mi * 16 + kg * 4 + r] = acc[mi][ni][r];
        }
      }
      __syncthreads();
      #pragma unroll
      for (int j = 0; j < 4; ++j) {
        const int f  = j * 512 + tid;                // 0..2047
        const int cp = f >> 6;                       // 0..31
        const int p4 = (f & 63) * 4;                 // 0..252
        const f32x4 v = *(const f32x4*)&Tl[cp * 260 + p4];
        *(f32x4*)&Out[obase + (size_t)(tileN + ch * 32 + cp) * 1024 + p4] = v;
      }
    }
  }
#undef PH_SYNC
#undef PH_END
#undef PH_END_VM
}

// ---------------------------------------------------------------------------
// Dual-B GEMM (Kd=512): accW = xt@W^T and accT = xt@TW^T in one pass over A.
// Epilogue: WxBf = bf16(accW); uA = bf16(st(accT) + accW)  (accW in f32).
// ---------------------------------------------------------------------------
__global__ __launch_bounds__(512, 2) void gemm_dual_kernel(
    const bf16_t* __restrict__ A, const bf16_t* __restrict__ B1,
    const bf16_t* __restrict__ B2,
    bf16_t* __restrict__ WxOut, bf16_t* __restrict__ UOut,
    const float* __restrict__ thresh_p)
{
  __shared__ __align__(16) char smem[131072];
  bf16_t* lds = (bf16_t*)smem;   // buf stride 32768 elems; B1 +16384, B2 +24576

  const int tid = threadIdx.x;
  const int wid = tid >> 6, lane = tid & 63;
  const int wr = wid >> 1, wc = wid & 1;
  const int lr = lane & 15, kg = lane >> 4;

  const int per = gridDim.x >> 3;
  const int logical = (blockIdx.x & 7) * per + (blockIdx.x >> 3);
  const int tileN = (logical & 7) << 7;
  const int tileM = (logical >> 3) << 8;

  size_t offA[4]; int dstA[4];
  #pragma unroll
  for (int j = 0; j < 4; ++j) {
    const int f = j * 512 + tid;
    const int row = f >> 3, u = f & 7;
    const int ug = u ^ (row & 7);
    offA[j] = (size_t)(tileM + row) * 512 + ug * 8;
    dstA[j] = f * 8;
  }
  size_t offB[2]; int dstB1[2], dstB2[2];
  #pragma unroll
  for (int j = 0; j < 2; ++j) {
    const int f = j * 512 + tid;
    const int col = f >> 3, u = f & 7;
    const int ug = u ^ (col & 7);
    offB[j] = (size_t)(tileN + col) * 512 + ug * 8;
    dstB1[j] = 16384 + f * 8;
    dstB2[j] = 24576 + f * 8;
  }

  auto readA = [&](int mi, int ks, int bs) -> bf16x8 {
    const int R = wr * 64 + mi * 16 + lr;
    const int ul = (ks * 4 + kg) ^ (R & 7);
    return *(const bf16x8*)(lds + bs + R * 64 + ul * 8);
  };
  auto readB = [&](int boff, int ni, int ks, int bs) -> bf16x8 {
    const int C = wc * 64 + ni * 16 + lr;
    const int ul = (ks * 4 + kg) ^ (C & 7);
    return *(const bf16x8*)(lds + bs + boff + C * 64 + ul * 8);
  };

  f32x4 accW[4][4] = {}, accT[4][4] = {};
  bf16x8 af[4], bw[4], bt[4];

  auto stageTile = [&](int ts, int sbs) {
    const size_t ko = (size_t)ts << 6;
    #pragma unroll
    for (int j = 0; j < 4; ++j) GLOAD_LDS16(A + offA[j] + ko, lds + sbs + dstA[j]);
    #pragma unroll
    for (int j = 0; j < 2; ++j) GLOAD_LDS16(B1 + offB[j] + ko, lds + sbs + dstB1[j]);
    #pragma unroll
    for (int j = 0; j < 2; ++j) GLOAD_LDS16(B2 + offB[j] + ko, lds + sbs + dstB2[j]);
  };

  stageTile(0, 0);
  asm volatile("s_waitcnt vmcnt(0)" ::: "memory");
  __builtin_amdgcn_s_barrier();

  for (int t = 0; t < 8; ++t) {                  // NT = 512/64
    const int bs  = (t & 1) << 15;
    const int sbs = bs ^ 32768;
    stageTile((t + 1 < 8) ? t + 1 : 0, sbs);     // wrap refetch benign

    #pragma unroll
    for (int ks = 0; ks < 2; ++ks) {
      #pragma unroll
      for (int mi = 0; mi < 4; ++mi) af[mi] = readA(mi, ks, bs);
      #pragma unroll
      for (int ni = 0; ni < 4; ++ni) bw[ni] = readB(16384, ni, ks, bs);
      #pragma unroll
      for (int ni = 0; ni < 4; ++ni) bt[ni] = readB(24576, ni, ks, bs);
      #pragma unroll
      for (int mi = 0; mi < 4; ++mi)
        #pragma unroll
        for (int ni = 0; ni < 4; ++ni) {
          accW[mi][ni] = MFMA(af[mi], bw[ni], accW[mi][ni]);
          accT[mi][ni] = MFMA(af[mi], bt[ni], accT[mi][ni]);
        }
    }

    asm volatile("s_waitcnt vmcnt(0)" ::: "memory");   // tile t+1 landed
    __builtin_amdgcn_s_barrier();
  }

  const float th = *thresh_p;
  asm volatile("s_waitcnt vmcnt(0)" ::: "memory");     // wrap stages landed
  __syncthreads();
  float* Tl = (float*)smem;                            // [32][132] f32

  #pragma unroll
  for (int c = 0; c < 8; ++c) {                        // 32-row chunks
    if (c) __syncthreads();
    if (wr == (c >> 1)) {
      #pragma unroll
      for (int mj = 0; mj < 2; ++mj) {
        const int mi = (c & 1) * 2 + mj;
        const int rl = mj * 16 + kg * 4;
        #pragma unroll
        for (int ni = 0; ni < 4; ++ni) {
          const int cl = wc * 64 + ni * 16 + lr;
          #pragma unroll
          for (int r = 0; r < 4; ++r)
            Tl[(rl + r) * 132 + cl] = accW[mi][ni][r];
        }
      }
    }
    __syncthreads();
    f32x4 vw[2];
    #pragma unroll
    for (int j = 0; j < 2; ++j) {
      const int f  = j * 512 + tid;
      const int rl = f >> 5;
      const int c4 = (f & 31) * 4;
      vw[j] = *(const f32x4*)&Tl[rl * 132 + c4];
      const int grow = tileM + c * 32 + rl;
      const size_t gidx = (size_t)grow * 1024 + tileN + c4;
      bf16x4 ov;
      #pragma unroll
      for (int e = 0; e < 4; ++e) ov[e] = (bf16_t)vw[j][e];
      *(bf16x4*)&WxOut[gidx] = ov;
    }
    __syncthreads();
    if (wr == (c >> 1)) {
      #pragma unroll
      for (int mj = 0; mj < 2; ++mj) {
        const int mi = (c & 1) * 2 + mj;
        const int rl = mj * 16 + kg * 4;
        #pragma unroll
        for (int ni = 0; ni < 4; ++ni) {
          const int cl = wc * 64 + ni * 16 + lr;
          #pragma unroll
          for (int r = 0; r < 4; ++r)
            Tl[(rl + r) * 132 + cl] = accT[mi][ni][r];
        }
      }
    }
    __syncthreads();
    #pragma unroll
    for (int j = 0; j < 2; ++j) {
      const int f  = j * 512 + tid;
      const int rl = f >> 5;
      const int c4 = (f & 31) * 4;
      const f32x4 vt = *(const f32x4*)&Tl[rl * 132 + c4];
      const int grow = tileM + c * 32 + rl;
      const size_t gidx = (size_t)grow * 1024 + tileN + c4;
      bf16x4 ov;
      #pragma unroll
      for (int e = 0; e < 4; ++e) {
        const float a  = fabsf(vt[e]) - th;
        const float zn = (a > 0.f) ? copysignf(a, vt[e]) : 0.f;
        ov[e] = (bf16_t)(zn + vw[j][e]);
      }
      *(bf16x4*)&UOut[gidx] = ov;
    }
  }
}

// ---------------------------------------------------------------------------
// Mini-GEMM: TW[i][c] = sum_j T[i][j] * Wt[c][j].  One wave per 16x16 tile,
// direct global->VGPR (both operands L2-resident), 2048 waves = 8/CU.
// ---------------------------------------------------------------------------
__global__ __launch_bounds__(256) void tw_gemm_kernel(
    const bf16_t* __restrict__ Tb,   // [1024][1024]
    const bf16_t* __restrict__ Wt,   // [512][1024]
    bf16_t* __restrict__ TW)         // [1024][512]
{
  const int tid = threadIdx.x;
  const int wid = tid >> 6, lane = tid & 63;
  const int lr = lane & 15, kg = lane >> 4;
  const int tile = blockIdx.x * 4 + wid;        // 0..2047
  const int ci = tile & 31;
  const int ii = tile >> 5;
  const int i0 = ii * 16, c0 = ci * 16;

  const bf16_t* pa = Tb + (size_t)(i0 + lr) * 1024 + kg * 8;
  const bf16_t* pb = Wt + (size_t)(c0 + lr) * 1024 + kg * 8;

  f32x4 acc = {};
  #pragma unroll 4
  for (int t = 0; t < 32; ++t) {
    const bf16x8 a = *(const bf16x8*)(pa + t * 32);
    const bf16x8 b = *(const bf16x8*)(pb + t * 32);
    acc = MFMA(a, b, acc);
  }
  #pragma unroll
  for (int r = 0; r < 4; ++r)
    TW[(size_t)(i0 + kg * 4 + r) * 512 + c0 + lr] = (bf16_t)acc[r];
}

// Fused: T = bf16(I - S) over [1024][1024], and Wbf = bf16(W) for idx<512k.
__global__ void make_T_castW_kernel(const float* __restrict__ S,
                                    bf16_t* __restrict__ T,
                                    const float* __restrict__ W,
                                    bf16_t* __restrict__ Wb) {
  const int idx = blockIdx.x * blockDim.x + threadIdx.x;
  const int i = idx >> 10, j = idx & 1023;
  T[idx] = (bf16_t)(((i == j) ? 1.0f : 0.0f) - S[idx]);
  if (idx < 524288) Wb[idx] = (bf16_t)W[idx];
}

// x [B][C=512][P=1024] f32 -> xt [b*1024+p][c] bf16
__global__ void transpose_cast_x_kernel(const float* __restrict__ x,
                                        bf16_t* __restrict__ xt) {
  __shared__ float t[32][33];
  const int b  = blockIdx.z;
  const int p0 = blockIdx.x * 32;
  const int c0 = blockIdx.y * 32;
  const int tx = threadIdx.x, ty = threadIdx.y;
  #pragma unroll
  for (int i = 0; i < 32; i += 8)
    t[ty + i][tx] = x[((size_t)b * 512 + c0 + ty + i) * 1024 + p0 + tx];
  __syncthreads();
  #pragma unroll
  for (int i = 0; i < 32; i += 8)
    xt[((size_t)b * 1024 + p0 + ty + i) * 512 + c0 + tx] = (bf16_t)t[tx][ty + i];
}

// Wt[c][j] = W[j][c], f32 [1024][512] -> bf16 [512][1024]
__global__ void transpose_cast_w_kernel(const float* __restrict__ W,
                                        bf16_t* __restrict__ Wt) {
  __shared__ float t[32][33];
  const int j0 = blockIdx.x * 32;
  const int c0 = blockIdx.y * 32;
  const int tx = threadIdx.x, ty = threadIdx.y;
  #pragma unroll
  for (int i = 0; i < 32; i += 8)
    t[ty + i][tx] = W[(size_t)(j0 + ty + i) * 512 + c0 + tx];
  __syncthreads();
  #pragma unroll
  for (int i = 0; i < 32; i += 8)
    Wt[(size_t)(c0 + ty + i) * 1024 + j0 + tx] = (bf16_t)t[tx][ty + i];
}

__global__ void dict_norm_kernel(const float* __restrict__ dict,
                                 float* __restrict__ out) {
  const int row = blockIdx.x;
  const int tid = threadIdx.x;
  const float* r = dict + (size_t)row * 512;
  float s = 0.f;
  for (int i = tid; i < 512; i += 256) { float v = r[i]; s += v * v; }
  #pragma unroll
  for (int off = 32; off > 0; off >>= 1) s += __shfl_down(s, off);
  __shared__ float ps[4];
  if ((tid & 63) == 0) ps[tid >> 6] = s;
  __syncthreads();
  const float inv = 1.0f / sqrtf(ps[0] + ps[1] + ps[2] + ps[3]);
  for (int i = tid; i < 512; i += 256) out[(size_t)row * 512 + i] = r[i] * inv;
}

extern "C" void kernel_launch(void* const* d_in, const int* in_sizes, int n_in,
                              void* d_out, int out_size, void* d_ws, size_t ws_size,
                              hipStream_t stream) {
  const float* x      = (const float*)d_in[0];  // [32,512,32,32]
  const float* dict   = (const float*)d_in[1];  // [1024,512]
  const float* W      = (const float*)d_in[2];  // [1024,512]
  const float* S      = (const float*)d_in[3];  // [1024,1024]
  const float* thresh = (const float*)d_in[4];  // scalar

  float* out = (float*)d_out;

  char* ws = (char*)d_ws;
  bf16_t* uA   = (bf16_t*)ws;                     //  67,108,864 B [32768][1024]
  bf16_t* uB   = (bf16_t*)(ws + 67108864);        //  67,108,864 B
  bf16_t* WxBf = (bf16_t*)(ws + 134217728);       //  67,108,864 B
  bf16_t* xt   = (bf16_t*)(ws + 201326592);       //  33,554,432 B [32768][512]
  bf16_t* Wbf  = (bf16_t*)(ws + 234881024);       //   1,048,576 B
  bf16_t* Tbf  = (bf16_t*)(ws + 235929600);       //   2,097,152 B (end 238,026,752)

  // Temporaries in d_out's z-region (overwritten by mode-2 at the end).
  bf16_t* WtBf = (bf16_t*)out;                    //   1,048,576 B [512][1024]
  bf16_t* TWbf = WtBf + 524288;                   //   1,048,576 B [1024][512]
  float* dnorm = out + 33554432;                  // dict_norm region (disjoint)

  make_T_castW_kernel<<<dim3(2048), dim3(512), 0, stream>>>(S, Tbf, W, Wbf);
  transpose_cast_w_kernel<<<dim3(32, 16), dim3(32, 8), 0, stream>>>(W, WtBf);
  tw_gemm_kernel<<<dim3(512), dim3(256), 0, stream>>>(Tbf, WtBf, TWbf);
  transpose_cast_x_kernel<<<dim3(32, 16, 32), dim3(32, 8), 0, stream>>>(x, xt);
  dict_norm_kernel<<<dim3(1024), dim3(256), 0, stream>>>(dict, dnorm);

  // Fused: Wx = xt@W^T  AND  u2 = st(xt@TW^T) + Wx   (Kd=512)
  gemm_dual_kernel<<<dim3(1024), dim3(512), 0, stream>>>(
      xt, Wbf, TWbf, WxBf, uA, thresh);

  // steps 2..4: u' = st(T@u) + Wx   (8-phase 256^2 kernel, grid 512)
  bf16_t* uc = uA; bf16_t* un = uB;
  for (int s = 0; s < 3; ++s) {
    gemm8_kernel<<<dim3(512), dim3(512), 0, stream>>>(
        uc, Tbf, 1024, 1, WxBf, un, nullptr, thresh);
    bf16_t* tmp = uc; uc = un; un = tmp;
  }
  // step 5: z = st(T@u), fused transpose to out[b][k][p]
  gemm8_kernel<<<dim3(512), dim3(512), 0, stream>>>(
      uc, Tbf, 1024, 2, nullptr, nullptr, out, thresh);
}

// Round 19
// 503.020 us; speedup vs baseline: 1.0594x; 1.0594x over previous
//
#include <hip/hip_runtime.h>
#include <hip/hip_bf16.h>

typedef __bf16 bf16_t;
typedef __bf16 bf16x4 __attribute__((ext_vector_type(4)));
typedef __bf16 bf16x8 __attribute__((ext_vector_type(8)));
typedef float f32x4 __attribute__((ext_vector_type(4)));

#define GLOAD_LDS16(g, l)                                                      \
  __builtin_amdgcn_global_load_lds(                                            \
      (const __attribute__((address_space(1))) void*)(g),                      \
      (__attribute__((address_space(3))) void*)(l), 16, 0, 0)

#define MFMA(a, b, c) __builtin_amdgcn_mfma_f32_16x16x32_bf16((a), (b), (c), 0, 0, 0)

// ---------------------------------------------------------------------------
// ROUND 19 = FINAL = r15/r17 (session best: 504.9-511.7us, absmax 0.375).
// r18's faithful m201 8-phase port regressed (533us; step 150us) -- the
// EIGHTH structural K-loop variant to land at >= the r6/r15 3-buf loop's
// ~92-105us/step. Conclusion: for this narrow-N (1024) shape class the
// plain-HIP plateau is the r15 structure; counters show no saturated pipe
// (MfmaUtil 27%, HBM 20%, LDS ~36%, 0 conflicts) -- composite latency/sync
// bound; the documented path past it (hand-asm K-loop) is out of scope.
// Session: 1401 -> ~505us (2.78x) via bf16-MFMA formulation, u-only LISTA
// algebra (u' = st(T@u) + Wx, T = I-S), TW=T@W precompute (step1 K=512),
// dual-B fusion (Wx GEMM + step1 share one A pass), write-ideal BK=64
// 3-buf pipelined GEMM (counted vmcnt, raw barriers, XOR swizzle, repack
// epilogues with full-line stores), fused output transpose.
// ---------------------------------------------------------------------------
__global__ __launch_bounds__(512, 2) void gemm_kernel(
    const bf16_t* __restrict__ A, const bf16_t* __restrict__ Bt,
    int Kd, int Nc, int mode,
    const bf16_t* __restrict__ WxIn, bf16_t* __restrict__ UnextOrWx,
    float* __restrict__ Out, const float* __restrict__ thresh_p)
{
  __shared__ __align__(16) char smem[147456];
  bf16_t* lds = (bf16_t*)smem;           // buf stride 24576 elems; B at +16384

  const int tid = threadIdx.x;
  const int wid = tid >> 6, lane = tid & 63;
  const int wr = wid >> 1, wc = wid & 1;         // 4M x 2N wave grid
  const int lr = lane & 15, kg = lane >> 4;

  const int per = gridDim.x >> 3;
  const int logical = (blockIdx.x & 7) * per + (blockIdx.x >> 3);
  const int ntn = Nc >> 7;
  const int tileN = (logical % ntn) << 7;
  const int tileM = (logical / ntn) << 8;
  const int NT = Kd >> 6;

  size_t offA[4]; int dstA[4];
  #pragma unroll
  for (int j = 0; j < 4; ++j) {
    const int f = j * 512 + tid;                 // 0..2047
    const int row = f >> 3, u = f & 7;
    const int ug = u ^ (row & 7);
    offA[j] = (size_t)(tileM + row) * Kd + ug * 8;
    dstA[j] = f * 8;
  }
  size_t offB[2]; int dstB[2];
  #pragma unroll
  for (int j = 0; j < 2; ++j) {
    const int f = j * 512 + tid;                 // 0..1023
    const int col = f >> 3, u = f & 7;
    const int ug = u ^ (col & 7);
    offB[j] = (size_t)(tileN + col) * Kd + ug * 8;
    dstB[j] = 16384 + f * 8;
  }

  auto readA = [&](int mi, int ks, int bs) -> bf16x8 {
    const int R = wr * 64 + mi * 16 + lr;
    const int ul = (ks * 4 + kg) ^ (R & 7);
    return *(const bf16x8*)(lds + bs + R * 64 + ul * 8);
  };
  auto readB = [&](int ni, int ks, int bs) -> bf16x8 {
    const int C = wc * 64 + ni * 16 + lr;
    const int ul = (ks * 4 + kg) ^ (C & 7);
    return *(const bf16x8*)(lds + bs + 16384 + C * 64 + ul * 8);
  };

  f32x4 acc[4][4] = {};
  bf16x8 a0[4], b0[4], a1[4], b1[4];

  #pragma unroll
  for (int j = 0; j < 4; ++j) GLOAD_LDS16(A + offA[j], lds + dstA[j]);
  #pragma unroll
  for (int j = 0; j < 2; ++j) GLOAD_LDS16(Bt + offB[j], lds + dstB[j]);
  if (NT > 1) {
    #pragma unroll
    for (int j = 0; j < 4; ++j) GLOAD_LDS16(A + offA[j] + 64, lds + 24576 + dstA[j]);
    #pragma unroll
    for (int j = 0; j < 2; ++j) GLOAD_LDS16(Bt + offB[j] + 64, lds + 24576 + dstB[j]);
  }
  asm volatile("s_waitcnt vmcnt(6)" ::: "memory");   // tile 0 landed
  __builtin_amdgcn_s_barrier();

  int buf = 0, sb3 = 2;                              // t%3, (t+2)%3
  for (int t = 0; t < NT; ++t) {
    const int bs = buf * 24576;
    const int sbs = sb3 * 24576;
    const int ts = (t + 2 < NT) ? t + 2 : t + 2 - NT;   // wrap refetch (benign)
    const size_t ko = (size_t)ts << 6;

    GLOAD_LDS16(A + offA[0] + ko, lds + sbs + dstA[0]);
    GLOAD_LDS16(A + offA[1] + ko, lds + sbs + dstA[1]);
    GLOAD_LDS16(A + offA[2] + ko, lds + sbs + dstA[2]);
    GLOAD_LDS16(A + offA[3] + ko, lds + sbs + dstA[3]);
    GLOAD_LDS16(Bt + offB[0] + ko, lds + sbs + dstB[0]);
    GLOAD_LDS16(Bt + offB[1] + ko, lds + sbs + dstB[1]);

    #pragma unroll
    for (int mi = 0; mi < 4; ++mi) a0[mi] = readA(mi, 0, bs);
    #pragma unroll
    for (int ni = 0; ni < 4; ++ni) b0[ni] = readB(ni, 0, bs);
    #pragma unroll
    for (int mi = 0; mi < 4; ++mi) a1[mi] = readA(mi, 1, bs);
    #pragma unroll
    for (int ni = 0; ni < 4; ++ni) b1[ni] = readB(ni, 1, bs);

    #pragma unroll
    for (int mi = 0; mi < 4; ++mi)
      #pragma unroll
      for (int ni = 0; ni < 4; ++ni)
        acc[mi][ni] = MFMA(a0[mi], b0[ni], acc[mi][ni]);
    #pragma unroll
    for (int mi = 0; mi < 4; ++mi)
      #pragma unroll
      for (int ni = 0; ni < 4; ++ni)
        acc[mi][ni] = MFMA(a1[mi], b1[ni], acc[mi][ni]);

    asm volatile("s_waitcnt vmcnt(6)" ::: "memory");   // tile t+1 landed
    __builtin_amdgcn_s_barrier();                      // raw: no drain

    buf = (buf == 2) ? 0 : buf + 1;
    sb3 = (sb3 == 2) ? 0 : sb3 + 1;
  }

  const float th = *thresh_p;

  if (mode <= 1) {
    asm volatile("s_waitcnt vmcnt(0)" ::: "memory");   // wrap stages landed
    __syncthreads();
    float* Tl = (float*)smem;                          // [32][132] f32
    #pragma unroll
    for (int c = 0; c < 8; ++c) {                      // 32-row chunks
      if (c) __syncthreads();
      if (wr == (c >> 1)) {
        #pragma unroll
        for (int mj = 0; mj < 2; ++mj) {
          const int mi = (c & 1) * 2 + mj;
          const int rl = mj * 16 + kg * 4;
          #pragma unroll
          for (int ni = 0; ni < 4; ++ni) {
            const int cl = wc * 64 + ni * 16 + lr;
            #pragma unroll
            for (int r = 0; r < 4; ++r)
              Tl[(rl + r) * 132 + cl] = acc[mi][ni][r];
          }
        }
      }
      __syncthreads();
      #pragma unroll
      for (int j = 0; j < 2; ++j) {
        const int f  = j * 512 + tid;                  // 0..1023
        const int rl = f >> 5;                         // 0..31
        const int c4 = (f & 31) * 4;                   // 0..124
        const f32x4 v = *(const f32x4*)&Tl[rl * 132 + c4];
        const int grow = tileM + c * 32 + rl;
        const size_t gidx = (size_t)grow * Nc + tileN + c4;
        bf16x4 ov;
        if (mode == 1) {
          const bf16x4 wx = *(const bf16x4*)&WxIn[gidx];
          #pragma unroll
          for (int e = 0; e < 4; ++e) {
            const float a  = fabsf(v[e]) - th;
            const float zn = (a > 0.f) ? copysignf(a, v[e]) : 0.f;
            ov[e] = (bf16_t)(zn + (float)wx[e]);
          }
        } else {
          #pragma unroll
          for (int e = 0; e < 4; ++e) ov[e] = (bf16_t)v[e];
        }
        *(bf16x4*)&UnextOrWx[gidx] = ov;
      }
    }
  } else {
    // mode 2 (Nc==1024): z = st(acc), fused transpose -> Out[b][k][p].
    #pragma unroll
    for (int mi = 0; mi < 4; ++mi)
      #pragma unroll
      for (int ni = 0; ni < 4; ++ni)
        #pragma unroll
        for (int r = 0; r < 4; ++r) {
          const float v = acc[mi][ni][r];
          const float a = fabsf(v) - th;
          acc[mi][ni][r] = (a > 0.f) ? copysignf(a, v) : 0.f;
        }
    asm volatile("s_waitcnt vmcnt(0)" ::: "memory");
    __syncthreads();
    float* Tl = (float*)smem;                          // [32][260] f32
    const int    bb    = tileM >> 10;
    const size_t obase = (size_t)bb * 1048576 + (size_t)(tileM & 1023);
    #pragma unroll
    for (int ch = 0; ch < 4; ++ch) {                   // 32-k-col chunks
      if (ch) __syncthreads();
      if (wc == (ch >> 1)) {
        #pragma unroll
        for (int nj = 0; nj < 2; ++nj) {
          const int ni = (ch & 1) * 2 + nj;
          const int cp = nj * 16 + lr;                 // 0..31
          #pragma unroll
          for (int mi = 0; mi < 4; ++mi)
            #pragma unroll
            for (int r = 0; r < 4; ++r)
              Tl[cp * 260 + wr * 64 + mi * 16 + kg * 4 + r] = acc[mi][ni][r];
        }
      }
      __syncthreads();
      #pragma unroll
      for (int j = 0; j < 4; ++j) {
        const int f  = j * 512 + tid;                  // 0..2047
        const int cp = f >> 6;                         // 0..31
        const int p4 = (f & 63) * 4;                   // 0..252
        const f32x4 v = *(const f32x4*)&Tl[cp * 260 + p4];
        *(f32x4*)&Out[obase + (size_t)(tileN + ch * 32 + cp) * 1024 + p4] = v;
      }
    }
  }
}

// ---------------------------------------------------------------------------
// Dual-B GEMM (Kd=512): accW = xt@W^T and accT = xt@TW^T in one pass over A.
// Epilogue: WxBf = bf16(accW); uA = bf16(st(accT) + accW)  (accW in f32).
// ---------------------------------------------------------------------------
__global__ __launch_bounds__(512, 2) void gemm_dual_kernel(
    const bf16_t* __restrict__ A, const bf16_t* __restrict__ B1,
    const bf16_t* __restrict__ B2,
    bf16_t* __restrict__ WxOut, bf16_t* __restrict__ UOut,
    const float* __restrict__ thresh_p)
{
  __shared__ __align__(16) char smem[131072];
  bf16_t* lds = (bf16_t*)smem;   // buf stride 32768 elems; B1 +16384, B2 +24576

  const int tid = threadIdx.x;
  const int wid = tid >> 6, lane = tid & 63;
  const int wr = wid >> 1, wc = wid & 1;
  const int lr = lane & 15, kg = lane >> 4;

  const int per = gridDim.x >> 3;
  const int logical = (blockIdx.x & 7) * per + (blockIdx.x >> 3);
  const int tileN = (logical & 7) << 7;
  const int tileM = (logical >> 3) << 8;

  size_t offA[4]; int dstA[4];
  #pragma unroll
  for (int j = 0; j < 4; ++j) {
    const int f = j * 512 + tid;
    const int row = f >> 3, u = f & 7;
    const int ug = u ^ (row & 7);
    offA[j] = (size_t)(tileM + row) * 512 + ug * 8;
    dstA[j] = f * 8;
  }
  size_t offB[2]; int dstB1[2], dstB2[2];
  #pragma unroll
  for (int j = 0; j < 2; ++j) {
    const int f = j * 512 + tid;
    const int col = f >> 3, u = f & 7;
    const int ug = u ^ (col & 7);
    offB[j] = (size_t)(tileN + col) * 512 + ug * 8;
    dstB1[j] = 16384 + f * 8;
    dstB2[j] = 24576 + f * 8;
  }

  auto readA = [&](int mi, int ks, int bs) -> bf16x8 {
    const int R = wr * 64 + mi * 16 + lr;
    const int ul = (ks * 4 + kg) ^ (R & 7);
    return *(const bf16x8*)(lds + bs + R * 64 + ul * 8);
  };
  auto readB = [&](int boff, int ni, int ks, int bs) -> bf16x8 {
    const int C = wc * 64 + ni * 16 + lr;
    const int ul = (ks * 4 + kg) ^ (C & 7);
    return *(const bf16x8*)(lds + bs + boff + C * 64 + ul * 8);
  };

  f32x4 accW[4][4] = {}, accT[4][4] = {};
  bf16x8 af[4], bw[4], bt[4];

  auto stageTile = [&](int ts, int sbs) {
    const size_t ko = (size_t)ts << 6;
    #pragma unroll
    for (int j = 0; j < 4; ++j) GLOAD_LDS16(A + offA[j] + ko, lds + sbs + dstA[j]);
    #pragma unroll
    for (int j = 0; j < 2; ++j) GLOAD_LDS16(B1 + offB[j] + ko, lds + sbs + dstB1[j]);
    #pragma unroll
    for (int j = 0; j < 2; ++j) GLOAD_LDS16(B2 + offB[j] + ko, lds + sbs + dstB2[j]);
  };

  stageTile(0, 0);
  asm volatile("s_waitcnt vmcnt(0)" ::: "memory");
  __builtin_amdgcn_s_barrier();

  for (int t = 0; t < 8; ++t) {                  // NT = 512/64
    const int bs  = (t & 1) << 15;
    const int sbs = bs ^ 32768;
    stageTile((t + 1 < 8) ? t + 1 : 0, sbs);     // wrap refetch benign

    #pragma unroll
    for (int ks = 0; ks < 2; ++ks) {
      #pragma unroll
      for (int mi = 0; mi < 4; ++mi) af[mi] = readA(mi, ks, bs);
      #pragma unroll
      for (int ni = 0; ni < 4; ++ni) bw[ni] = readB(16384, ni, ks, bs);
      #pragma unroll
      for (int ni = 0; ni < 4; ++ni) bt[ni] = readB(24576, ni, ks, bs);
      #pragma unroll
      for (int mi = 0; mi < 4; ++mi)
        #pragma unroll
        for (int ni = 0; ni < 4; ++ni) {
          accW[mi][ni] = MFMA(af[mi], bw[ni], accW[mi][ni]);
          accT[mi][ni] = MFMA(af[mi], bt[ni], accT[mi][ni]);
        }
    }

    asm volatile("s_waitcnt vmcnt(0)" ::: "memory");   // tile t+1 landed
    __builtin_amdgcn_s_barrier();
  }

  const float th = *thresh_p;
  asm volatile("s_waitcnt vmcnt(0)" ::: "memory");     // wrap stages landed
  __syncthreads();
  float* Tl = (float*)smem;                            // [32][132] f32

  #pragma unroll
  for (int c = 0; c < 8; ++c) {                        // 32-row chunks
    if (c) __syncthreads();
    if (wr == (c >> 1)) {
      #pragma unroll
      for (int mj = 0; mj < 2; ++mj) {
        const int mi = (c & 1) * 2 + mj;
        const int rl = mj * 16 + kg * 4;
        #pragma unroll
        for (int ni = 0; ni < 4; ++ni) {
          const int cl = wc * 64 + ni * 16 + lr;
          #pragma unroll
          for (int r = 0; r < 4; ++r)
            Tl[(rl + r) * 132 + cl] = accW[mi][ni][r];
        }
      }
    }
    __syncthreads();
    f32x4 vw[2];
    #pragma unroll
    for (int j = 0; j < 2; ++j) {
      const int f  = j * 512 + tid;
      const int rl = f >> 5;
      const int c4 = (f & 31) * 4;
      vw[j] = *(const f32x4*)&Tl[rl * 132 + c4];
      const int grow = tileM + c * 32 + rl;
      const size_t gidx = (size_t)grow * 1024 + tileN + c4;
      bf16x4 ov;
      #pragma unroll
      for (int e = 0; e < 4; ++e) ov[e] = (bf16_t)vw[j][e];
      *(bf16x4*)&WxOut[gidx] = ov;
    }
    __syncthreads();
    if (wr == (c >> 1)) {
      #pragma unroll
      for (int mj = 0; mj < 2; ++mj) {
        const int mi = (c & 1) * 2 + mj;
        const int rl = mj * 16 + kg * 4;
        #pragma unroll
        for (int ni = 0; ni < 4; ++ni) {
          const int cl = wc * 64 + ni * 16 + lr;
          #pragma unroll
          for (int r = 0; r < 4; ++r)
            Tl[(rl + r) * 132 + cl] = accT[mi][ni][r];
        }
      }
    }
    __syncthreads();
    #pragma unroll
    for (int j = 0; j < 2; ++j) {
      const int f  = j * 512 + tid;
      const int rl = f >> 5;
      const int c4 = (f & 31) * 4;
      const f32x4 vt = *(const f32x4*)&Tl[rl * 132 + c4];
      const int grow = tileM + c * 32 + rl;
      const size_t gidx = (size_t)grow * 1024 + tileN + c4;
      bf16x4 ov;
      #pragma unroll
      for (int e = 0; e < 4; ++e) {
        const float a  = fabsf(vt[e]) - th;
        const float zn = (a > 0.f) ? copysignf(a, vt[e]) : 0.f;
        ov[e] = (bf16_t)(zn + vw[j][e]);
      }
      *(bf16x4*)&UOut[gidx] = ov;
    }
  }
}

// ---------------------------------------------------------------------------
// Mini-GEMM: TW[i][c] = sum_j T[i][j] * Wt[c][j].  One wave per 16x16 tile,
// direct global->VGPR (both operands L2-resident), 2048 waves = 8/CU.
// ---------------------------------------------------------------------------
__global__ __launch_bounds__(256) void tw_gemm_kernel(
    const bf16_t* __restrict__ Tb,   // [1024][1024]
    const bf16_t* __restrict__ Wt,   // [512][1024]
    bf16_t* __restrict__ TW)         // [1024][512]
{
  const int tid = threadIdx.x;
  const int wid = tid >> 6, lane = tid & 63;
  const int lr = lane & 15, kg = lane >> 4;
  const int tile = blockIdx.x * 4 + wid;        // 0..2047
  const int ci = tile & 31;
  const int ii = tile >> 5;
  const int i0 = ii * 16, c0 = ci * 16;

  const bf16_t* pa = Tb + (size_t)(i0 + lr) * 1024 + kg * 8;
  const bf16_t* pb = Wt + (size_t)(c0 + lr) * 1024 + kg * 8;

  f32x4 acc = {};
  #pragma unroll 4
  for (int t = 0; t < 32; ++t) {
    const bf16x8 a = *(const bf16x8*)(pa + t * 32);
    const bf16x8 b = *(const bf16x8*)(pb + t * 32);
    acc = MFMA(a, b, acc);
  }
  #pragma unroll
  for (int r = 0; r < 4; ++r)
    TW[(size_t)(i0 + kg * 4 + r) * 512 + c0 + lr] = (bf16_t)acc[r];
}

// Fused: T = bf16(I - S) over [1024][1024], and Wbf = bf16(W) for idx<512k.
__global__ void make_T_castW_kernel(const float* __restrict__ S,
                                    bf16_t* __restrict__ T,
                                    const float* __restrict__ W,
                                    bf16_t* __restrict__ Wb) {
  const int idx = blockIdx.x * blockDim.x + threadIdx.x;
  const int i = idx >> 10, j = idx & 1023;
  T[idx] = (bf16_t)(((i == j) ? 1.0f : 0.0f) - S[idx]);
  if (idx < 524288) Wb[idx] = (bf16_t)W[idx];
}

// x [B][C=512][P=1024] f32 -> xt [b*1024+p][c] bf16
__global__ void transpose_cast_x_kernel(const float* __restrict__ x,
                                        bf16_t* __restrict__ xt) {
  __shared__ float t[32][33];
  const int b  = blockIdx.z;
  const int p0 = blockIdx.x * 32;
  const int c0 = blockIdx.y * 32;
  const int tx = threadIdx.x, ty = threadIdx.y;
  #pragma unroll
  for (int i = 0; i < 32; i += 8)
    t[ty + i][tx] = x[((size_t)b * 512 + c0 + ty + i) * 1024 + p0 + tx];
  __syncthreads();
  #pragma unroll
  for (int i = 0; i < 32; i += 8)
    xt[((size_t)b * 1024 + p0 + ty + i) * 512 + c0 + tx] = (bf16_t)t[tx][ty + i];
}

// Wt[c][j] = W[j][c], f32 [1024][512] -> bf16 [512][1024]
__global__ void transpose_cast_w_kernel(const float* __restrict__ W,
                                        bf16_t* __restrict__ Wt) {
  __shared__ float t[32][33];
  const int j0 = blockIdx.x * 32;
  const int c0 = blockIdx.y * 32;
  const int tx = threadIdx.x, ty = threadIdx.y;
  #pragma unroll
  for (int i = 0; i < 32; i += 8)
    t[ty + i][tx] = W[(size_t)(j0 + ty + i) * 512 + c0 + tx];
  __syncthreads();
  #pragma unroll
  for (int i = 0; i < 32; i += 8)
    Wt[(size_t)(c0 + ty + i) * 1024 + j0 + tx] = (bf16_t)t[tx][ty + i];
}

__global__ void dict_norm_kernel(const float* __restrict__ dict,
                                 float* __restrict__ out) {
  const int row = blockIdx.x;
  const int tid = threadIdx.x;
  const float* r = dict + (size_t)row * 512;
  float s = 0.f;
  for (int i = tid; i < 512; i += 256) { float v = r[i]; s += v * v; }
  #pragma unroll
  for (int off = 32; off > 0; off >>= 1) s += __shfl_down(s, off);
  __shared__ float ps[4];
  if ((tid & 63) == 0) ps[tid >> 6] = s;
  __syncthreads();
  const float inv = 1.0f / sqrtf(ps[0] + ps[1] + ps[2] + ps[3]);
  for (int i = tid; i < 512; i += 256) out[(size_t)row * 512 + i] = r[i] * inv;
}

extern "C" void kernel_launch(void* const* d_in, const int* in_sizes, int n_in,
                              void* d_out, int out_size, void* d_ws, size_t ws_size,
                              hipStream_t stream) {
  const float* x      = (const float*)d_in[0];  // [32,512,32,32]
  const float* dict   = (const float*)d_in[1];  // [1024,512]
  const float* W      = (const float*)d_in[2];  // [1024,512]
  const float* S      = (const float*)d_in[3];  // [1024,1024]
  const float* thresh = (const float*)d_in[4];  // scalar

  float* out = (float*)d_out;

  char* ws = (char*)d_ws;
  bf16_t* uA   = (bf16_t*)ws;                     //  67,108,864 B [32768][1024]
  bf16_t* uB   = (bf16_t*)(ws + 67108864);        //  67,108,864 B
  bf16_t* WxBf = (bf16_t*)(ws + 134217728);       //  67,108,864 B
  bf16_t* xt   = (bf16_t*)(ws + 201326592);       //  33,554,432 B [32768][512]
  bf16_t* Wbf  = (bf16_t*)(ws + 234881024);       //   1,048,576 B
  bf16_t* Tbf  = (bf16_t*)(ws + 235929600);       //   2,097,152 B (end 238,026,752)

  // Temporaries in d_out's z-region (overwritten by mode-2 at the end).
  bf16_t* WtBf = (bf16_t*)out;                    //   1,048,576 B [512][1024]
  bf16_t* TWbf = WtBf + 524288;                   //   1,048,576 B [1024][512]
  float* dnorm = out + 33554432;                  // dict_norm region (disjoint)

  make_T_castW_kernel<<<dim3(2048), dim3(512), 0, stream>>>(S, Tbf, W, Wbf);
  transpose_cast_w_kernel<<<dim3(32, 16), dim3(32, 8), 0, stream>>>(W, WtBf);
  tw_gemm_kernel<<<dim3(512), dim3(256), 0, stream>>>(Tbf, WtBf, TWbf);
  transpose_cast_x_kernel<<<dim3(32, 16, 32), dim3(32, 8), 0, stream>>>(x, xt);
  dict_norm_kernel<<<dim3(1024), dim3(256), 0, stream>>>(dict, dnorm);

  // Fused: Wx = xt@W^T  AND  u2 = st(xt@TW^T) + Wx   (Kd=512)
  gemm_dual_kernel<<<dim3(1024), dim3(512), 0, stream>>>(
      xt, Wbf, TWbf, WxBf, uA, thresh);

  // steps 2..4: u' = st(T@u) + Wx
  bf16_t* uc = uA; bf16_t* un = uB;
  for (int s = 0; s < 3; ++s) {
    gemm_kernel<<<dim3(1024), dim3(512), 0, stream>>>(
        uc, Tbf, 1024, 1024, 1, WxBf, un, nullptr, thresh);
    bf16_t* tmp = uc; uc = un; un = tmp;
  }
  // step 5: z = st(T@u), fused transpose to out[b][k][p]
  gemm_kernel<<<dim3(1024), dim3(512), 0, stream>>>(
      uc, Tbf, 1024, 1024, 2, nullptr, nullptr, out, thresh);
}